// Round 8
// baseline (146.737 us; speedup 1.0000x reference)
//
#include <hip/hip_runtime.h>
#include <hip/hip_bf16.h>
#include <math.h>

namespace {
constexpr int kB = 16, kT = 2048, kC = 512, kH = 4, kU = 250, kDH = 128;
constexpr int kDS = 4;          // d-split blocks per (b,h)
constexpr int kDW = 32;         // d per block
constexpr int kTT = 256;        // t-tile staged per iteration
constexpr int kNST = kT / kTT;  // 8
constexpr int kPitch = 264;     // bT row pitch in shorts (16B-aligned rows, 2-way bank alias only)
}

typedef __attribute__((ext_vector_type(8))) short short8;
typedef __attribute__((ext_vector_type(4))) float float4v;

__device__ __forceinline__ short f2bf(float x) {
    union { float f; unsigned int u; } v; v.f = x;
    unsigned int r = (v.u + 0x7FFFu + ((v.u >> 16) & 1u)) >> 16;
    return (short)r;
}

// ---------------- K1: alpha prediction branch ----------------
// wave = 8 consecutive t of one b; 10 hidden rows kept in registers (1.25x read amp).
__global__ __launch_bounds__(256) void k1_alpha(
    const float* __restrict__ hid, const float* __restrict__ mask,
    const float* __restrict__ conv_w, const float* __restrict__ conv_b,
    const float* __restrict__ lin_w, const float* __restrict__ lin_b,
    float* __restrict__ alpha_raw)
{
    const int wave = threadIdx.x >> 6, lane = threadIdx.x & 63;
    const int gw = blockIdx.x * 4 + wave;
    const int b = gw >> 8;                 // 256 waves per b
    const int t0 = (gw & 255) << 3;
    const int c0 = lane * 8;

    float cw[24], cb[8], lw[8];
    #pragma unroll
    for (int i = 0; i < 6; i++) *(float4*)&cw[i*4] = ((const float4*)(conv_w + c0*3))[i];
    *(float4*)&cb[0] = *(const float4*)(conv_b + c0);
    *(float4*)&cb[4] = *(const float4*)(conv_b + c0 + 4);
    *(float4*)&lw[0] = *(const float4*)(lin_w + c0);
    *(float4*)&lw[4] = *(const float4*)(lin_w + c0 + 4);
    const float lb = lin_b[0];

    float r[10][8];
    const float* base = hid + ((size_t)b * kT + t0) * kC + c0;
    #pragma unroll
    for (int i = 0; i < 10; i++) {
        const int tt = t0 + i - 1;
        if (tt >= 0 && tt < kT) {
            const float* p = base + (ptrdiff_t)(i - 1) * kC;
            *(float4*)&r[i][0] = *(const float4*)p;
            *(float4*)&r[i][4] = *(const float4*)(p + 4);
        } else {
            #pragma unroll
            for (int j = 0; j < 8; j++) r[i][j] = 0.f;
        }
    }

    float sums[8];
    #pragma unroll
    for (int j = 0; j < 8; j++) {
        float acc = 0.f;
        #pragma unroll
        for (int k = 0; k < 8; k++) {
            float m = fmaf(r[j][k], cw[k*3],
                      fmaf(r[j+1][k], cw[k*3+1],
                      fmaf(r[j+2][k], cw[k*3+2], cb[k])));
            float v = m + r[j+1][k];          // memory + context
            v = v > 0.f ? v : 0.f;            // relu
            acc = fmaf(v, lw[k], acc);
        }
        #pragma unroll
        for (int off = 32; off >= 1; off >>= 1) acc += __shfl_xor(acc, off, 64);
        sums[j] = acc;
    }
    if (lane == 0) {
        #pragma unroll
        for (int j = 0; j < 8; j++) {
            float s = sums[j] + lb;
            float a = 1.f / (1.f + expf(-s));  // relu(sigmoid*1-0) == sigmoid
            alpha_raw[(size_t)b * kT + t0 + j] = a * mask[(size_t)b * kT + t0 + j];
        }
    }
}

// ---------------- K3: MFMA Gaussian soft-segment attention ----------------
// grid (u2*ds = 8, h = 4, b = 16) = 512 blocks (2/CU) x 512 thr (8 waves).
// Block owns u-half [u2*128, +128) x d-slice [ds*32, +32) of head h => disjoint
// output, no atomics. Wave = 16 u x 32 d (2 n-tiles).
// The k2 scan (token_num / scale / cumsum) is recomputed per block in LDS
// (deterministic, identical across blocks); block (0,0,b) writes tok/alphas.
// Per-u softmax max exact via binary search on monotone alignment; per-wave
// contributing t-range from the e>=1e-9-of-max band |du-al| <= sqrt(dmin^2+21/s^2);
// block-level band skips whole 256-t staging tiles.
__global__ __launch_bounds__(512) void k3_attn(
    const float* __restrict__ hid, const float* __restrict__ alpha_raw,
    const float* __restrict__ mask, const int* __restrict__ target,
    const float* __restrict__ sigma,
    float* __restrict__ out_ac, float* __restrict__ out_tok, float* __restrict__ out_alpha)
{
    __shared__ float al_s[kT];                    // 8 KB
    __shared__ unsigned short bT[kDW * kPitch];   // 16.9 KB, [d][t] bf16
    __shared__ float woff[8];
    __shared__ float s_tot;
    __shared__ int wlo[8], whi[8];
    __shared__ int s_blo, s_bhi;

    const int u2 = blockIdx.x & 1, ds = blockIdx.x >> 1;
    const int h = blockIdx.y, b = blockIdx.z;
    const int tid = threadIdx.x;
    const int wave = tid >> 6, lane = tid & 63;
    const int lm = lane & 15, quad = lane >> 4;
    const float sig = sigma[h];

    // ---- inline k2: block scan of alpha -> al_s (mask-folded alignment) ----
    float4 av = ((const float4*)(alpha_raw + (size_t)b * kT))[tid];
    float pre[4];
    pre[0] = av.x; pre[1] = pre[0] + av.y; pre[2] = pre[1] + av.z; pre[3] = pre[2] + av.w;
    const float s = pre[3];
    float sc = s;
    #pragma unroll
    for (int off = 1; off <= 32; off <<= 1) {
        float v = __shfl_up(sc, off, 64);
        sc = (lane >= off) ? sc + v : sc;
    }
    if (lane == 63) woff[wave] = sc;
    __syncthreads();
    if (tid == 0) {
        float run = 0.f;
        #pragma unroll
        for (int w = 0; w < 8; w++) { float x = woff[w]; woff[w] = run; run += x; }
        s_tot = run;
    }
    __syncthreads();
    const float tot = s_tot;
    const float scale = (tot != 0.f) ? ((float)target[b] / tot) : 0.f;
    const float basev = woff[wave] + (sc - s);
    float4 mv = ((const float4*)(mask + (size_t)b * kT))[tid];
    {
        float alv[4];
        const float* mp = (const float*)&mv;
        #pragma unroll
        for (int j = 0; j < 4; j++) {
            float cum = (basev + pre[j]) * scale;
            alv[j] = (mp[j] > 0.f) ? cum : 1.0e30f;
        }
        *(float4*)&al_s[tid * 4] = *(float4*)&alv[0];
    }
    if (blockIdx.x == 0 && h == 0) {
        if (tid == 0) out_tok[b] = tot;
        float4 oa;
        oa.x = av.x * scale; oa.y = av.y * scale; oa.z = av.z * scale; oa.w = av.w * scale;
        ((float4*)(out_alpha + (size_t)b * kT))[tid] = oa;
    }
    __syncthreads();

    // ---- per-lane u: exact softmax max via binary search (al_s monotone) ----
    const int u_base = u2 * 128 + wave * 16;
    const float du = (float)(u_base + lm) + 0.5f;
    const float dusig = du * sig;
    int pos = 0;
    #pragma unroll
    for (int stp = 1024; stp >= 1; stp >>= 1) {
        int np = pos + stp;
        pos = (al_s[np - 1] < du) ? np : pos;
    }
    float d1 = (pos < kT) ? al_s[pos] - du : 3.0e30f;     // may be negative for tail u
    float d0 = (pos > 0) ? du - al_s[pos - 1] : 3.0e30f;
    float dmin = fminf(d0, d1);                            // |dmin| = true min distance
    float ms = fminf(dmin, 1.0e4f) * sig;
    const float mu_pos = ms * ms;                          // = -max_score (>= 0)

    // wave band: |du - al| <= sqrt(dmax^2 + 21/sig^2)  (e >= 1e-9 of max term)
    float dmax_l = dmin;
    #pragma unroll
    for (int off = 8; off >= 1; off >>= 1) dmax_l = fmaxf(dmax_l, __shfl_xor(dmax_l, off, 64));
    const float c21 = (sig > 1e-3f) ? 21.0f / (sig * sig) : 9.0e60f;
    const float bound = sqrtf(fmaf(dmax_l, dmax_l, c21));
    const float lo_b = (float)u_base + 0.5f - bound;
    const float hi_b = (float)u_base + 15.5f + bound;
    int p_lo = 0, p_hi = 0;
    #pragma unroll
    for (int stp = 1024; stp >= 1; stp >>= 1) {
        int n1 = p_lo + stp; p_lo = (al_s[n1 - 1] < lo_b) ? n1 : p_lo;
        int n2 = p_hi + stp; p_hi = (al_s[n2 - 1] < hi_b) ? n2 : p_hi;
    }
    const int ks_lo = p_lo >> 5;            // first contributing 32-chunk
    const int ks_end = (p_hi + 31) >> 5;    // exclusive
    if (lane == 0) { wlo[wave] = p_lo; whi[wave] = p_hi; }
    __syncthreads();
    if (tid == 0) {
        int lo = kT, hi = 0;
        #pragma unroll
        for (int w = 0; w < 8; w++) { lo = min(lo, wlo[w]); hi = max(hi, whi[w]); }
        s_blo = lo; s_bhi = hi;
    }
    __syncthreads();
    const int blk_lo = s_blo, blk_hi = s_bhi;

    float4v acc0 = (float4v)(0.f), acc1 = (float4v)(0.f);
    float lsum = 0.f;

    // staging mapping: thread -> 2 t-rows x 8 d
    const int tl = (tid & 127) * 2;
    const int dbase = (tid >> 7) * 8;
    const float* hrow = hid + (size_t)b * kT * kC + h * kDH + ds * kDW + dbase;

    for (int st = 0; st < kNST; st++) {
        const int t_lo = st * kTT;
        if (t_lo + kTT <= blk_lo || t_lo >= blk_hi) continue;   // block-uniform tile skip
        __syncthreads();                 // previous tile's readers done
        {
            const float* src = hrow + (size_t)(t_lo + tl) * kC;
            float4 a0 = *(const float4*)src;
            float4 a1 = *(const float4*)(src + 4);
            float4 b0 = *(const float4*)(src + kC);
            float4 b1 = *(const float4*)(src + kC + 4);
            const float* p0 = (const float*)&a0;
            const float* p1 = (const float*)&b0;
            #pragma unroll
            for (int e = 0; e < 4; e++) {
                unsigned int lo = (unsigned int)(unsigned short)f2bf(p0[e]);
                unsigned int hi = (unsigned int)(unsigned short)f2bf(p1[e]);
                *(unsigned int*)&bT[(dbase + e) * kPitch + tl] = lo | (hi << 16);
            }
            p0 = (const float*)&a1; p1 = (const float*)&b1;
            #pragma unroll
            for (int e = 0; e < 4; e++) {
                unsigned int lo = (unsigned int)(unsigned short)f2bf(p0[e]);
                unsigned int hi = (unsigned int)(unsigned short)f2bf(p1[e]);
                *(unsigned int*)&bT[(dbase + 4 + e) * kPitch + tl] = lo | (hi << 16);
            }
        }
        __syncthreads();

        #pragma unroll
        for (int ks = 0; ks < 8; ks++) {
            const int kg = st * 8 + ks;
            if (kg < ks_lo || kg >= ks_end) continue;   // wave-uniform band skip
            const int kb = kg * 32;

            float alv[8];
            *(float4*)&alv[0] = *(const float4*)&al_s[kb + quad * 8];
            *(float4*)&alv[4] = *(const float4*)&al_s[kb + quad * 8 + 4];

            short8 afrag;
            #pragma unroll
            for (int j = 0; j < 8; j++) {
                float d = fmaf(-alv[j], sig, dusig);      // (du - al) * sig
                float e = __expf(fmaf(-d, d, mu_pos));    // exp(max - d^2) <= 1
                lsum += e;
                afrag[j] = f2bf(e);
            }
            short8 bf0 = *(const short8*)&bT[lm * kPitch + ks * 32 + quad * 8];
            short8 bf1 = *(const short8*)&bT[(16 + lm) * kPitch + ks * 32 + quad * 8];
            acc0 = __builtin_amdgcn_mfma_f32_16x16x32_bf16(afrag, bf0, acc0, 0, 0, 0);
            acc1 = __builtin_amdgcn_mfma_f32_16x16x32_bf16(afrag, bf1, acc1, 0, 0, 0);
        }
    }

    // epilogue: reduce l across quads, normalize, direct store (disjoint => no atomics)
    float lv = lsum;
    lv += __shfl_xor(lv, 16, 64);
    lv += __shfl_xor(lv, 32, 64);        // every lane: full l for u = u_base + lm
    #pragma unroll
    for (int r = 0; r < 4; r++) {
        const int ur = quad * 4 + r;
        float rl = __shfl(lv, ur, 64);   // l for u = u_base + ur
        float linv = (rl > 1e-30f) ? 1.f / rl : 0.f;
        const int u = u_base + ur;
        if (u < kU) {
            float* dst = out_ac + ((size_t)(b * kU + u)) * kC + h * kDH + ds * kDW + lm;
            dst[0]  = acc0[r] * linv;
            dst[16] = acc1[r] * linv;
        }
    }
}

extern "C" void kernel_launch(void* const* d_in, const int* in_sizes, int n_in,
                              void* d_out, int out_size, void* d_ws, size_t ws_size,
                              hipStream_t stream) {
    const float* hid    = (const float*)d_in[0];
    const float* mask   = (const float*)d_in[1];
    const int*   tgt    = (const int*)d_in[2];
    // d_in[3] = max_token scalar (compile-time kU=250)
    const float* conv_w = (const float*)d_in[4];
    const float* conv_b = (const float*)d_in[5];
    const float* lin_w  = (const float*)d_in[6];
    const float* lin_b  = (const float*)d_in[7];
    const float* sigma  = (const float*)d_in[8];
    // d_in[9] = sigma_bias: constant over t -> cancels in softmax; unused.

    float* alpha_raw = (float*)d_ws;                     // [B*T]

    float* out_ac    = (float*)d_out;                    // [B, U, C]
    float* out_tok   = out_ac + (size_t)kB * kU * kC;    // [B]
    float* out_alpha = out_tok + kB;                     // [B, T]

    k1_alpha<<<kB * kT / 32, 256, 0, stream>>>(hid, mask, conv_w, conv_b, lin_w, lin_b, alpha_raw);
    k3_attn<<<dim3(2 * kDS, kH, kB), 512, 0, stream>>>(hid, alpha_raw, mask, tgt, sigma,
                                                       out_ac, out_tok, out_alpha);
}

// Round 9
// 132.652 us; speedup vs baseline: 1.1062x; 1.1062x over previous
//
#include <hip/hip_runtime.h>
#include <hip/hip_bf16.h>
#include <math.h>

namespace {
constexpr int kB = 16, kT = 2048, kC = 512, kH = 4, kU = 250, kDH = 128;
constexpr int kDS = 4;          // d-split blocks per (b,h)
constexpr int kDW = 32;         // d per block
constexpr int kTT = 256;        // t-tile staged per iteration
constexpr int kNST = kT / kTT;  // 8
constexpr int kPitch = 264;     // bT row pitch in shorts (16B-aligned rows)
}

typedef __attribute__((ext_vector_type(8))) short short8;
typedef __attribute__((ext_vector_type(4))) float float4v;

__device__ __forceinline__ short f2bf(float x) {
    union { float f; unsigned int u; } v; v.f = x;
    unsigned int r = (v.u + 0x7FFFu + ((v.u >> 16) & 1u)) >> 16;
    return (short)r;
}

// ---------------- K1: alpha prediction branch ----------------
// wave = 8 consecutive t of one b; 10 hidden rows kept in registers (1.25x read amp).
__global__ __launch_bounds__(256) void k1_alpha(
    const float* __restrict__ hid, const float* __restrict__ mask,
    const float* __restrict__ conv_w, const float* __restrict__ conv_b,
    const float* __restrict__ lin_w, const float* __restrict__ lin_b,
    float* __restrict__ alpha_raw)
{
    const int wave = threadIdx.x >> 6, lane = threadIdx.x & 63;
    const int gw = blockIdx.x * 4 + wave;
    const int b = gw >> 8;                 // 256 waves per b
    const int t0 = (gw & 255) << 3;
    const int c0 = lane * 8;

    float cw[24], cb[8], lw[8];
    #pragma unroll
    for (int i = 0; i < 6; i++) *(float4*)&cw[i*4] = ((const float4*)(conv_w + c0*3))[i];
    *(float4*)&cb[0] = *(const float4*)(conv_b + c0);
    *(float4*)&cb[4] = *(const float4*)(conv_b + c0 + 4);
    *(float4*)&lw[0] = *(const float4*)(lin_w + c0);
    *(float4*)&lw[4] = *(const float4*)(lin_w + c0 + 4);
    const float lb = lin_b[0];

    float r[10][8];
    const float* base = hid + ((size_t)b * kT + t0) * kC + c0;
    #pragma unroll
    for (int i = 0; i < 10; i++) {
        const int tt = t0 + i - 1;
        if (tt >= 0 && tt < kT) {
            const float* p = base + (ptrdiff_t)(i - 1) * kC;
            *(float4*)&r[i][0] = *(const float4*)p;
            *(float4*)&r[i][4] = *(const float4*)(p + 4);
        } else {
            #pragma unroll
            for (int j = 0; j < 8; j++) r[i][j] = 0.f;
        }
    }

    float sums[8];
    #pragma unroll
    for (int j = 0; j < 8; j++) {
        float acc = 0.f;
        #pragma unroll
        for (int k = 0; k < 8; k++) {
            float m = fmaf(r[j][k], cw[k*3],
                      fmaf(r[j+1][k], cw[k*3+1],
                      fmaf(r[j+2][k], cw[k*3+2], cb[k])));
            float v = m + r[j+1][k];          // memory + context
            v = v > 0.f ? v : 0.f;            // relu
            acc = fmaf(v, lw[k], acc);
        }
        #pragma unroll
        for (int off = 32; off >= 1; off >>= 1) acc += __shfl_xor(acc, off, 64);
        sums[j] = acc;
    }
    if (lane == 0) {
        #pragma unroll
        for (int j = 0; j < 8; j++) {
            float s = sums[j] + lb;
            float a = 1.f / (1.f + expf(-s));  // relu(sigmoid*1-0) == sigmoid
            alpha_raw[(size_t)b * kT + t0 + j] = a * mask[(size_t)b * kT + t0 + j];
        }
    }
}

// ---------------- K3: MFMA Gaussian soft-segment attention ----------------
// grid (ds=4, h=4, b=16) = 256 blocks x 1024 thr (16 waves, 4 waves/SIMD).
// Block owns d-slice [ds*32, +32) of head h, loops full T => disjoint output,
// no atomics, hidden read exactly once. Wave = 16 u x 32 d (2 n-tiles).
// k2 scan (token_num/scale/cumsum) recomputed per block in LDS (deterministic);
// block (0, h=0, b) writes tok/alphas. Per-u softmax max exact via binary search
// on monotone alignment; per-wave band |du-al| <= sqrt(dmin^2 + 21/sig^2).
// bT double-buffered: ONE barrier per tile, prefetch overlaps compute.
__global__ __launch_bounds__(1024) void k3_attn(
    const float* __restrict__ hid, const float* __restrict__ alpha_raw,
    const float* __restrict__ mask, const int* __restrict__ target,
    const float* __restrict__ sigma,
    float* __restrict__ out_ac, float* __restrict__ out_tok, float* __restrict__ out_alpha)
{
    __shared__ float al_s[kT];                       // 8 KB
    __shared__ unsigned short bT[2][kDW * kPitch];   // 33.8 KB, [buf][d][t] bf16
    __shared__ float woff[16];
    __shared__ float s_tot;

    const int ds = blockIdx.x, h = blockIdx.y, b = blockIdx.z;
    const int tid = threadIdx.x;
    const int wave = tid >> 6, lane = tid & 63;
    const int lm = lane & 15, quad = lane >> 4;
    const float sig = sigma[h];

    // ---- inline k2: block scan of alpha -> al_s (mask-folded alignment) ----
    float2 av = ((const float2*)(alpha_raw + (size_t)b * kT))[tid];
    const float p0 = av.x, p1 = av.x + av.y;
    const float s = p1;
    float sc = s;
    #pragma unroll
    for (int off = 1; off <= 32; off <<= 1) {
        float v = __shfl_up(sc, off, 64);
        sc = (lane >= off) ? sc + v : sc;
    }
    if (lane == 63) woff[wave] = sc;
    __syncthreads();
    if (tid == 0) {
        float run = 0.f;
        #pragma unroll
        for (int w = 0; w < 16; w++) { float x = woff[w]; woff[w] = run; run += x; }
        s_tot = run;
    }
    __syncthreads();
    const float tot = s_tot;
    const float scale = (tot != 0.f) ? ((float)target[b] / tot) : 0.f;
    const float basev = woff[wave] + (sc - s);
    float2 mv = ((const float2*)(mask + (size_t)b * kT))[tid];
    {
        float c0 = (basev + p0) * scale;
        float c1 = (basev + p1) * scale;
        float2 alv;
        alv.x = (mv.x > 0.f) ? c0 : 1.0e30f;
        alv.y = (mv.y > 0.f) ? c1 : 1.0e30f;
        ((float2*)al_s)[tid] = alv;
    }
    if (ds == 0 && h == 0) {
        if (tid == 0) out_tok[b] = tot;
        float2 oa; oa.x = av.x * scale; oa.y = av.y * scale;
        ((float2*)(out_alpha + (size_t)b * kT))[tid] = oa;
    }
    __syncthreads();

    // ---- per-lane u: exact softmax max via binary search (al_s monotone) ----
    const int u_base = wave * 16;
    const float du = (float)(u_base + lm) + 0.5f;
    const float dusig = du * sig;
    int pos = 0;
    #pragma unroll
    for (int stp = 1024; stp >= 1; stp >>= 1) {
        int np = pos + stp;
        pos = (al_s[np - 1] < du) ? np : pos;
    }
    float d1 = (pos < kT) ? al_s[pos] - du : 3.0e30f;
    float d0 = (pos > 0) ? du - al_s[pos - 1] : 3.0e30f;
    float dmin = fminf(d0, d1);
    float ms = fminf(dmin, 1.0e4f) * sig;
    const float mu_pos = ms * ms;                    // = -max_score (>= 0)

    // wave band: |du - al| <= sqrt(dmax^2 + 21/sig^2)  (term >= 1e-9 of max)
    float dmax_l = fminf(dmin, 1.0e4f);
    #pragma unroll
    for (int off = 8; off >= 1; off >>= 1) dmax_l = fmaxf(dmax_l, __shfl_xor(dmax_l, off, 64));
    const float c21 = (sig > 1e-3f) ? 21.0f / (sig * sig) : 9.0e60f;
    const float bound = sqrtf(fmaf(dmax_l, dmax_l, c21));
    const float lo_b = (float)u_base + 0.5f - bound;
    const float hi_b = (float)u_base + 15.5f + bound;
    int p_lo = 0, p_hi = 0;
    #pragma unroll
    for (int stp = 1024; stp >= 1; stp >>= 1) {
        int n1 = p_lo + stp; p_lo = (al_s[n1 - 1] < lo_b) ? n1 : p_lo;
        int n2 = p_hi + stp; p_hi = (al_s[n2 - 1] < hi_b) ? n2 : p_hi;
    }
    const int ks_lo = p_lo >> 5;            // first contributing 32-chunk (global)
    const int ks_end = (p_hi + 31) >> 5;    // exclusive

    float4v acc0 = (float4v)(0.f), acc1 = (float4v)(0.f);
    float lsum = 0.f;

    // coalesced staging mapping: dl = tid&7 (4 d each), p = tid>>3 (t-pair)
    // wave-load = 8 rows x 128 B contiguous segments
    const int dl = tid & 7;
    const int p  = tid >> 3;                // 0..127 -> t = 2p, 2p+1
    const float* hrow = hid + (size_t)b * kT * kC + h * kDH + ds * kDW + dl * 4;

    float4 a0, a1;
    {
        const float* src = hrow + (size_t)(2 * p) * kC;
        a0 = *(const float4*)src;
        a1 = *(const float4*)(src + kC);
    }

    int buf = 0;
    for (int st = 0; st < kNST; st++) {
        // write staged regs -> bT[buf]
        {
            const float* q0 = (const float*)&a0;
            const float* q1 = (const float*)&a1;
            #pragma unroll
            for (int e = 0; e < 4; e++) {
                unsigned int lo = (unsigned int)(unsigned short)f2bf(q0[e]);
                unsigned int hi = (unsigned int)(unsigned short)f2bf(q1[e]);
                *(unsigned int*)&bT[buf][(dl * 4 + e) * kPitch + 2 * p] = lo | (hi << 16);
            }
        }
        __syncthreads();                    // single barrier per tile
        if (st + 1 < kNST) {                // prefetch next tile into regs
            const float* src = hrow + (size_t)((st + 1) * kTT + 2 * p) * kC;
            a0 = *(const float4*)src;
            a1 = *(const float4*)(src + kC);
        }

        #pragma unroll
        for (int ks = 0; ks < 8; ks++) {
            const int kg = st * 8 + ks;
            if (kg < ks_lo || kg >= ks_end) continue;   // wave-uniform band skip
            const int kb = kg * 32;

            float alv[8];
            *(float4*)&alv[0] = *(const float4*)&al_s[kb + quad * 8];
            *(float4*)&alv[4] = *(const float4*)&al_s[kb + quad * 8 + 4];

            short8 afrag;
            #pragma unroll
            for (int j = 0; j < 8; j++) {
                float d = fmaf(-alv[j], sig, dusig);      // (du - al) * sig
                float e = __expf(fmaf(-d, d, mu_pos));    // exp(max - d^2) <= 1
                lsum += e;
                afrag[j] = f2bf(e);
            }
            short8 bf0 = *(const short8*)&bT[buf][lm * kPitch + ks * 32 + quad * 8];
            short8 bf1 = *(const short8*)&bT[buf][(16 + lm) * kPitch + ks * 32 + quad * 8];
            acc0 = __builtin_amdgcn_mfma_f32_16x16x32_bf16(afrag, bf0, acc0, 0, 0, 0);
            acc1 = __builtin_amdgcn_mfma_f32_16x16x32_bf16(afrag, bf1, acc1, 0, 0, 0);
        }
        buf ^= 1;
    }

    // epilogue: reduce l across quads, normalize, direct store (disjoint)
    float lv = lsum;
    lv += __shfl_xor(lv, 16, 64);
    lv += __shfl_xor(lv, 32, 64);        // every lane: full l for u = u_base + lm
    #pragma unroll
    for (int r = 0; r < 4; r++) {
        const int ur = quad * 4 + r;
        float rl = __shfl(lv, ur, 64);   // l for u = u_base + ur
        float linv = (rl > 1e-30f) ? 1.f / rl : 0.f;
        const int u = u_base + ur;
        if (u < kU) {
            float* dst = out_ac + ((size_t)(b * kU + u)) * kC + h * kDH + ds * kDW + lm;
            dst[0]  = acc0[r] * linv;
            dst[16] = acc1[r] * linv;
        }
    }
}

extern "C" void kernel_launch(void* const* d_in, const int* in_sizes, int n_in,
                              void* d_out, int out_size, void* d_ws, size_t ws_size,
                              hipStream_t stream) {
    const float* hid    = (const float*)d_in[0];
    const float* mask   = (const float*)d_in[1];
    const int*   tgt    = (const int*)d_in[2];
    // d_in[3] = max_token scalar (compile-time kU=250)
    const float* conv_w = (const float*)d_in[4];
    const float* conv_b = (const float*)d_in[5];
    const float* lin_w  = (const float*)d_in[6];
    const float* lin_b  = (const float*)d_in[7];
    const float* sigma  = (const float*)d_in[8];
    // d_in[9] = sigma_bias: constant over t -> cancels in softmax; unused.

    float* alpha_raw = (float*)d_ws;                     // [B*T]

    float* out_ac    = (float*)d_out;                    // [B, U, C]
    float* out_tok   = out_ac + (size_t)kB * kU * kC;    // [B]
    float* out_alpha = out_tok + kB;                     // [B, T]

    k1_alpha<<<kB * kT / 32, 256, 0, stream>>>(hid, mask, conv_w, conv_b, lin_w, lin_b, alpha_raw);
    k3_attn<<<dim3(kDS, kH, kB), 1024, 0, stream>>>(hid, alpha_raw, mask, tgt, sigma,
                                                    out_ac, out_tok, out_alpha);
}

// Round 10
// 131.236 us; speedup vs baseline: 1.1181x; 1.0108x over previous
//
#include <hip/hip_runtime.h>
#include <hip/hip_bf16.h>

namespace {
constexpr int kB = 16, kT = 2048, kC = 512, kH = 4, kU = 250, kDH = 128;
constexpr int kDS = 4;          // d-split blocks per (b,h)
constexpr int kDW = 32;         // d per block
constexpr int kTT = 256;        // t-tile staged per iteration
constexpr int kNST = kT / kTT;  // 8
constexpr int kPitch = 264;     // bT row pitch in shorts (16B-aligned rows)
}

typedef __attribute__((ext_vector_type(8))) short short8;
typedef __attribute__((ext_vector_type(4))) float float4v;

__device__ __forceinline__ short f2bf(float x) {
    union { float f; unsigned int u; } v; v.f = x;
    unsigned int r = (v.u + 0x7FFFu + ((v.u >> 16) & 1u)) >> 16;
    return (short)r;
}

// ---------------- K1: alpha prediction branch ----------------
// block = 4 waves = 32 consecutive t of one b. Each wave loads its 8 core rows;
// interior halo rows exchanged via LDS (only block-boundary halos hit HBM):
// 34 rows per 32 t (1.06x amp) vs 40 (1.25x) before.
__global__ __launch_bounds__(256) void k1_alpha(
    const float* __restrict__ hid, const float* __restrict__ mask,
    const float* __restrict__ conv_w, const float* __restrict__ conv_b,
    const float* __restrict__ lin_w, const float* __restrict__ lin_b,
    float* __restrict__ alpha_raw)
{
    __shared__ float halo[4][2][512];   // 16 KB: [wave][first/last core row][c]
    const int wave = threadIdx.x >> 6, lane = threadIdx.x & 63;
    const int b = blockIdx.x >> 6;             // 64 blocks per b
    const int tblk = (blockIdx.x & 63) << 5;   // 32 t per block
    const int t0 = tblk + wave * 8;
    const int c0 = lane * 8;

    float cw[24], cb[8], lw[8];
    #pragma unroll
    for (int i = 0; i < 6; i++) *(float4*)&cw[i*4] = ((const float4*)(conv_w + c0*3))[i];
    *(float4*)&cb[0] = *(const float4*)(conv_b + c0);
    *(float4*)&cb[4] = *(const float4*)(conv_b + c0 + 4);
    *(float4*)&lw[0] = *(const float4*)(lin_w + c0);
    *(float4*)&lw[4] = *(const float4*)(lin_w + c0 + 4);
    const float lb = lin_b[0];

    float r[10][8];
    const float* base = hid + ((size_t)b * kT + t0) * kC + c0;
    #pragma unroll
    for (int i = 1; i <= 8; i++) {              // core rows t0 .. t0+7
        const float* p = base + (ptrdiff_t)(i - 1) * kC;
        *(float4*)&r[i][0] = *(const float4*)p;
        *(float4*)&r[i][4] = *(const float4*)(p + 4);
    }
    // publish boundary core rows
    *(float4*)&halo[wave][0][c0]     = *(float4*)&r[1][0];
    *(float4*)&halo[wave][0][c0 + 4] = *(float4*)&r[1][4];
    *(float4*)&halo[wave][1][c0]     = *(float4*)&r[8][0];
    *(float4*)&halo[wave][1][c0 + 4] = *(float4*)&r[8][4];

    // block-boundary halos from HBM (or zeros at sequence edges)
    if (wave == 0) {
        if (tblk > 0) {
            const float* p = base - kC;
            *(float4*)&r[0][0] = *(const float4*)p;
            *(float4*)&r[0][4] = *(const float4*)(p + 4);
        } else {
            #pragma unroll
            for (int j = 0; j < 8; j++) r[0][j] = 0.f;
        }
    }
    if (wave == 3) {
        if (tblk + 32 < kT) {
            const float* p = base + 8 * kC;
            *(float4*)&r[9][0] = *(const float4*)p;
            *(float4*)&r[9][4] = *(const float4*)(p + 4);
        } else {
            #pragma unroll
            for (int j = 0; j < 8; j++) r[9][j] = 0.f;
        }
    }
    __syncthreads();
    if (wave > 0) {
        *(float4*)&r[0][0] = *(float4*)&halo[wave - 1][1][c0];
        *(float4*)&r[0][4] = *(float4*)&halo[wave - 1][1][c0 + 4];
    }
    if (wave < 3) {
        *(float4*)&r[9][0] = *(float4*)&halo[wave + 1][0][c0];
        *(float4*)&r[9][4] = *(float4*)&halo[wave + 1][0][c0 + 4];
    }

    float sums[8];
    #pragma unroll
    for (int j = 0; j < 8; j++) {
        float acc = 0.f;
        #pragma unroll
        for (int k = 0; k < 8; k++) {
            float m = fmaf(r[j][k], cw[k*3],
                      fmaf(r[j+1][k], cw[k*3+1],
                      fmaf(r[j+2][k], cw[k*3+2], cb[k])));
            float v = m + r[j+1][k];          // memory + context
            v = v > 0.f ? v : 0.f;            // relu
            acc = fmaf(v, lw[k], acc);
        }
        #pragma unroll
        for (int off = 32; off >= 1; off >>= 1) acc += __shfl_xor(acc, off, 64);
        sums[j] = acc;
    }
    if (lane == 0) {
        #pragma unroll
        for (int j = 0; j < 8; j++) {
            float s = sums[j] + lb;
            float a = 1.f / (1.f + expf(-s));  // relu(sigmoid*1-0) == sigmoid
            alpha_raw[(size_t)b * kT + t0 + j] = a * mask[(size_t)b * kT + t0 + j];
        }
    }
}

// ---------------- K3: MFMA Gaussian soft-segment attention ----------------
// grid (ds=4, h=4, b=16) = 256 blocks x 1024 thr (16 waves, 4 waves/SIMD).
// Block owns d-slice [ds*32, +32) of head h, loops full T => disjoint output,
// no atomics, hidden read exactly once. Wave = 16 u x 32 d (2 n-tiles).
// k2 scan (token_num/scale/cumsum) recomputed per block in LDS (deterministic);
// block (ds=0, h=0, b) writes tok/alphas. Per-u softmax max exact via binary
// search on monotone alignment; per-wave band |du-al| <= sqrt(dmin^2 + 21/sig^2).
// bT double-buffered: ONE barrier per tile; tile-0 global loads issued at kernel
// top so HBM latency hides behind the scan + searches.
__global__ __launch_bounds__(1024) void k3_attn(
    const float* __restrict__ hid, const float* __restrict__ alpha_raw,
    const float* __restrict__ mask, const int* __restrict__ target,
    const float* __restrict__ sigma,
    float* __restrict__ out_ac, float* __restrict__ out_tok, float* __restrict__ out_alpha)
{
    __shared__ float al_s[kT];                       // 8 KB
    __shared__ unsigned short bT[2][kDW * kPitch];   // 33.8 KB, [buf][d][t] bf16
    __shared__ float woff[16];
    __shared__ float s_tot;

    const int ds = blockIdx.x, h = blockIdx.y, b = blockIdx.z;
    const int tid = threadIdx.x;
    const int wave = tid >> 6, lane = tid & 63;
    const int lm = lane & 15, quad = lane >> 4;
    const float sig = sigma[h];

    // coalesced staging mapping: dl = tid&7 (4 d each), p = tid>>3 (t-pair)
    const int dl = tid & 7;
    const int p  = tid >> 3;                // 0..127 -> t = 2p, 2p+1
    const float* hrow = hid + (size_t)b * kT * kC + h * kDH + ds * kDW + dl * 4;

    // issue tile-0 V loads immediately (independent of the scan below)
    float4 a0, a1;
    {
        const float* src = hrow + (size_t)(2 * p) * kC;
        a0 = *(const float4*)src;
        a1 = *(const float4*)(src + kC);
    }

    // ---- inline k2: block scan of alpha -> al_s (mask-folded alignment) ----
    float2 av = ((const float2*)(alpha_raw + (size_t)b * kT))[tid];
    float2 mv = ((const float2*)(mask + (size_t)b * kT))[tid];
    const float p0 = av.x, p1 = av.x + av.y;
    const float s = p1;
    float sc = s;
    #pragma unroll
    for (int off = 1; off <= 32; off <<= 1) {
        float v = __shfl_up(sc, off, 64);
        sc = (lane >= off) ? sc + v : sc;
    }
    if (lane == 63) woff[wave] = sc;
    __syncthreads();
    if (tid == 0) {
        float run = 0.f;
        #pragma unroll
        for (int w = 0; w < 16; w++) { float x = woff[w]; woff[w] = run; run += x; }
        s_tot = run;
    }
    __syncthreads();
    const float tot = s_tot;
    const float scale = (tot != 0.f) ? ((float)target[b] / tot) : 0.f;
    const float basev = woff[wave] + (sc - s);
    {
        float c0 = (basev + p0) * scale;
        float c1 = (basev + p1) * scale;
        float2 alv;
        alv.x = (mv.x > 0.f) ? c0 : 1.0e30f;
        alv.y = (mv.y > 0.f) ? c1 : 1.0e30f;
        ((float2*)al_s)[tid] = alv;
    }
    if (ds == 0 && h == 0) {
        if (tid == 0) out_tok[b] = tot;
        float2 oa; oa.x = av.x * scale; oa.y = av.y * scale;
        ((float2*)(out_alpha + (size_t)b * kT))[tid] = oa;
    }
    __syncthreads();

    // ---- per-lane u: exact softmax max via binary search (al_s monotone) ----
    const int u_base = wave * 16;
    const float du = (float)(u_base + lm) + 0.5f;
    const float dusig = du * sig;
    int pos = 0;
    #pragma unroll
    for (int stp = 1024; stp >= 1; stp >>= 1) {
        int np = pos + stp;
        pos = (al_s[np - 1] < du) ? np : pos;
    }
    float d1 = (pos < kT) ? al_s[pos] - du : 3.0e30f;
    float d0 = (pos > 0) ? du - al_s[pos - 1] : 3.0e30f;
    float dmin = fminf(d0, d1);
    float ms = fminf(dmin, 1.0e4f) * sig;
    const float mu_pos = ms * ms;                    // = -max_score (>= 0)

    // wave band: |du - al| <= sqrt(dmax^2 + 21/sig^2)  (term >= 1e-9 of max)
    float dmax_l = fminf(dmin, 1.0e4f);
    #pragma unroll
    for (int off = 8; off >= 1; off >>= 1) dmax_l = fmaxf(dmax_l, __shfl_xor(dmax_l, off, 64));
    const float c21 = (sig > 1e-3f) ? 21.0f / (sig * sig) : 9.0e60f;
    const float bound = sqrtf(fmaf(dmax_l, dmax_l, c21));
    const float lo_b = (float)u_base + 0.5f - bound;
    const float hi_b = (float)u_base + 15.5f + bound;
    int p_lo = 0, p_hi = 0;
    #pragma unroll
    for (int stp = 1024; stp >= 1; stp >>= 1) {
        int n1 = p_lo + stp; p_lo = (al_s[n1 - 1] < lo_b) ? n1 : p_lo;
        int n2 = p_hi + stp; p_hi = (al_s[n2 - 1] < hi_b) ? n2 : p_hi;
    }
    const int ks_lo = p_lo >> 5;            // first contributing 32-chunk (global)
    const int ks_end = (p_hi + 31) >> 5;    // exclusive

    float4v acc0 = (float4v)(0.f), acc1 = (float4v)(0.f);
    float lsum = 0.f;

    int buf = 0;
    for (int st = 0; st < kNST; st++) {
        // write staged regs -> bT[buf]
        {
            const float* q0 = (const float*)&a0;
            const float* q1 = (const float*)&a1;
            #pragma unroll
            for (int e = 0; e < 4; e++) {
                unsigned int lo = (unsigned int)(unsigned short)f2bf(q0[e]);
                unsigned int hi = (unsigned int)(unsigned short)f2bf(q1[e]);
                *(unsigned int*)&bT[buf][(dl * 4 + e) * kPitch + 2 * p] = lo | (hi << 16);
            }
        }
        __syncthreads();                    // single barrier per tile
        if (st + 1 < kNST) {                // prefetch next tile into regs
            const float* src = hrow + (size_t)((st + 1) * kTT + 2 * p) * kC;
            a0 = *(const float4*)src;
            a1 = *(const float4*)(src + kC);
        }

        #pragma unroll
        for (int ks = 0; ks < 8; ks++) {
            const int kg = st * 8 + ks;
            if (kg < ks_lo || kg >= ks_end) continue;   // wave-uniform band skip
            const int kb = kg * 32;

            float alv[8];
            *(float4*)&alv[0] = *(const float4*)&al_s[kb + quad * 8];
            *(float4*)&alv[4] = *(const float4*)&al_s[kb + quad * 8 + 4];

            short8 afrag;
            #pragma unroll
            for (int j = 0; j < 8; j++) {
                float d = fmaf(-alv[j], sig, dusig);      // (du - al) * sig
                float e = __expf(fmaf(-d, d, mu_pos));    // exp(max - d^2) <= 1
                lsum += e;
                afrag[j] = f2bf(e);
            }
            short8 bf0 = *(const short8*)&bT[buf][lm * kPitch + ks * 32 + quad * 8];
            short8 bf1 = *(const short8*)&bT[buf][(16 + lm) * kPitch + ks * 32 + quad * 8];
            acc0 = __builtin_amdgcn_mfma_f32_16x16x32_bf16(afrag, bf0, acc0, 0, 0, 0);
            acc1 = __builtin_amdgcn_mfma_f32_16x16x32_bf16(afrag, bf1, acc1, 0, 0, 0);
        }
        buf ^= 1;
    }

    // epilogue: reduce l across quads, normalize, direct store (disjoint)
    float lv = lsum;
    lv += __shfl_xor(lv, 16, 64);
    lv += __shfl_xor(lv, 32, 64);        // every lane: full l for u = u_base + lm
    #pragma unroll
    for (int r = 0; r < 4; r++) {
        const int ur = quad * 4 + r;
        float rl = __shfl(lv, ur, 64);   // l for u = u_base + ur
        float linv = (rl > 1e-30f) ? 1.f / rl : 0.f;
        const int u = u_base + ur;
        if (u < kU) {
            float* dst = out_ac + ((size_t)(b * kU + u)) * kC + h * kDH + ds * kDW + lm;
            dst[0]  = acc0[r] * linv;
            dst[16] = acc1[r] * linv;
        }
    }
}

extern "C" void kernel_launch(void* const* d_in, const int* in_sizes, int n_in,
                              void* d_out, int out_size, void* d_ws, size_t ws_size,
                              hipStream_t stream) {
    const float* hid    = (const float*)d_in[0];
    const float* mask   = (const float*)d_in[1];
    const int*   tgt    = (const int*)d_in[2];
    // d_in[3] = max_token scalar (compile-time kU=250)
    const float* conv_w = (const float*)d_in[4];
    const float* conv_b = (const float*)d_in[5];
    const float* lin_w  = (const float*)d_in[6];
    const float* lin_b  = (const float*)d_in[7];
    const float* sigma  = (const float*)d_in[8];
    // d_in[9] = sigma_bias: constant over t -> cancels in softmax; unused.

    float* alpha_raw = (float*)d_ws;                     // [B*T]

    float* out_ac    = (float*)d_out;                    // [B, U, C]
    float* out_tok   = out_ac + (size_t)kB * kU * kC;    // [B]
    float* out_alpha = out_tok + kB;                     // [B, T]

    k1_alpha<<<kB * kT / 32, 256, 0, stream>>>(hid, mask, conv_w, conv_b, lin_w, lin_b, alpha_raw);
    k3_attn<<<dim3(kDS, kH, kB), 1024, 0, stream>>>(hid, alpha_raw, mask, tgt, sigma,
                                                    out_ac, out_tok, out_alpha);
}